// Round 2
// baseline (574.468 us; speedup 1.0000x reference)
//
#include <hip/hip_runtime.h>
#include <stdint.h>

#define DEVI __device__ __forceinline__

typedef __attribute__((ext_vector_type(8))) uint16_t u16x8;
typedef __attribute__((ext_vector_type(4))) uint16_t u16x4v;
typedef __attribute__((ext_vector_type(8))) __bf16 bf16x8;
typedef __attribute__((ext_vector_type(4))) float f32x4;

DEVI uint16_t f2bf(float x) {
  union { float f; uint32_t u; } v; v.f = x;
  return (uint16_t)((v.u + 0x7fffu + ((v.u >> 16) & 1u)) >> 16);
}

DEVI uint16_t f2bfn(float f) {
  __bf16 h = (__bf16)f;
  return __builtin_bit_cast(uint16_t, h);
}

DEVI f32x4 mfma16(u16x8 a, u16x8 b, f32x4 c) {
  return __builtin_amdgcn_mfma_f32_16x16x32_bf16(
      __builtin_bit_cast(bf16x8, a), __builtin_bit_cast(bf16x8, b), c, 0, 0, 0);
}

DEVI void async16(void* lds, const void* g) {
  __builtin_amdgcn_global_load_lds(
      (const __attribute__((address_space(1))) uint32_t*)g,
      (__attribute__((address_space(3))) uint32_t*)lds, 16, 0, 0);
}

// 1/sqrt(128) * log2(e): softmax computed in exp2 domain, scale folded into Q.
#define QSC 0.12751742925f

// ---------------- elementwise f32 -> bf16 ----------------
__global__ void cvt_f32_bf16(const float* __restrict__ in, uint16_t* __restrict__ out, int n4) {
  int i = blockIdx.x * blockDim.x + threadIdx.x;
  const int st = gridDim.x * blockDim.x;
  for (; i < n4; i += st) {
    float4 v = ((const float4*)in)[i];
    u16x4v o;
    o[0] = f2bf(v.x); o[1] = f2bf(v.y); o[2] = f2bf(v.z); o[3] = f2bf(v.w);
    ((u16x4v*)out)[i] = o;
  }
}

// ------------- transpose + convert: f32 [K][N] -> bf16 [N][K] -------------
__global__ void transp_cvt(const float* __restrict__ in, uint16_t* __restrict__ out,
                           int K, int N) {
  __shared__ float Ws[64][65];
  const int n0 = blockIdx.x * 64, k0 = blockIdx.y * 64;
  const int t = threadIdx.x;
  const int r = t >> 4, c = (t & 15) << 2;
#pragma unroll
  for (int it = 0; it < 4; ++it) {
    float4 v = *(const float4*)&in[(size_t)(k0 + it * 16 + r) * N + n0 + c];
    Ws[it * 16 + r][c] = v.x; Ws[it * 16 + r][c + 1] = v.y;
    Ws[it * 16 + r][c + 2] = v.z; Ws[it * 16 + r][c + 3] = v.w;
  }
  __syncthreads();
#pragma unroll
  for (int it = 0; it < 4; ++it) {
    const int rr = it * 16 + r;   // n index in tile
    const int cc = c;             // k index in tile
    ushort4 o;
    o.x = f2bf(Ws[cc][rr]);     o.y = f2bf(Ws[cc + 1][rr]);
    o.z = f2bf(Ws[cc + 2][rr]); o.w = f2bf(Ws[cc + 3][rr]);
    *(ushort4*)&out[(size_t)(n0 + rr) * K + k0 + cc] = o;
  }
}

// ---- transpose bf16: [BH][T][128] -> [BH][128][T], XOR-swizzled t-within-64 ----
__global__ void transp_v(const uint16_t* __restrict__ in, uint16_t* __restrict__ out, int T) {
  __shared__ uint16_t Vsm[64][72];
  const int t0 = blockIdx.x * 64, d0 = blockIdx.y * 64, bh = blockIdx.z;
  const uint16_t* ip = in + (size_t)bh * T * 128;
  uint16_t* op = out + (size_t)bh * 128 * T;
  const int t = threadIdx.x;
  const int r = t >> 3, c = (t & 7) << 3;
#pragma unroll
  for (int it = 0; it < 2; ++it) {
    u16x8 v = *(const u16x8*)&ip[(size_t)(t0 + it * 32 + r) * 128 + d0 + c];
#pragma unroll
    for (int j = 0; j < 8; ++j) Vsm[it * 32 + r][c + j] = v[j];
  }
  __syncthreads();
#pragma unroll
  for (int it = 0; it < 2; ++it) {
    const int rr = it * 32 + r;  // d index in tile
    const int cc = c;            // t index in tile (8-aligned)
    u16x8 o;
#pragma unroll
    for (int j = 0; j < 8; ++j) o[j] = Vsm[cc + j][rr];
    const int ccs = cc ^ (((d0 + rr) & 7) << 3);  // pre-swizzle for attn LDS reads
    *(u16x8*)&op[(size_t)(d0 + rr) * T + t0 + ccs] = o;
  }
}

// ------------- GEMM: C[M][N] = A[M][K] * Bt[N][K]^T + bias -------------
// EPI==0: scatter bf16 into q (scaled by QSC) / k (d-swizzled) / v layouts.
// EPI==1: f32 out[M][N].
template <int EPI>
__global__ __launch_bounds__(256, 2)
void gemm_bt(const uint16_t* __restrict__ A, const uint16_t* __restrict__ Bt,
             const float* __restrict__ bias, float* __restrict__ outF,
             uint16_t* __restrict__ q, uint16_t* __restrict__ kk, uint16_t* __restrict__ v,
             int M, int N, int K) {
  constexpr int BK = 32;
  __shared__ uint16_t As[128 * BK];
  __shared__ uint16_t Bs[128 * BK];
  // bijective XCD swizzle (grid sizes here are multiples of 8)
  int bid = (int)blockIdx.x;
  const int q8 = (int)gridDim.x >> 3;
  bid = (bid & 7) * q8 + (bid >> 3);
  const int nbn = N >> 7;
  const int brow = (bid / nbn) << 7;
  const int bcol = (bid % nbn) << 7;
  const int t = threadIdx.x;
  const int w = t >> 6, lane = t & 63;
  const int wr = ((w >> 1) << 6), wc = ((w & 1) << 6);
  const int lr = lane & 15, lk = (lane >> 4) << 3;
  const int sr = t >> 2;
  const int sc = (t & 3) << 3;

  f32x4 acc[4][4];
#pragma unroll
  for (int i = 0; i < 4; ++i)
#pragma unroll
    for (int j = 0; j < 4; ++j) acc[i][j] = f32x4{0.f, 0.f, 0.f, 0.f};

  const uint16_t* Ap = A + (size_t)(brow + sr) * K + sc;
  const uint16_t* Bp = Bt + (size_t)(bcol + sr) * K + sc;
  const size_t rowskip = (size_t)64 * K;

  for (int k0 = 0; k0 < K; k0 += BK) {
    async16(&As[sr * BK + sc], Ap + k0);
    async16(&As[(64 + sr) * BK + sc], Ap + rowskip + k0);
    async16(&Bs[sr * BK + sc], Bp + k0);
    async16(&Bs[(64 + sr) * BK + sc], Bp + rowskip + k0);
    __syncthreads();
    u16x8 af[4], bf[4];
#pragma unroll
    for (int i = 0; i < 4; ++i) af[i] = *(const u16x8*)&As[(wr + i * 16 + lr) * BK + lk];
#pragma unroll
    for (int j = 0; j < 4; ++j) bf[j] = *(const u16x8*)&Bs[(wc + j * 16 + lr) * BK + lk];
#pragma unroll
    for (int i = 0; i < 4; ++i)
#pragma unroll
      for (int j = 0; j < 4; ++j) acc[i][j] = mfma16(af[i], bf[j], acc[i][j]);
    __syncthreads();
  }

#pragma unroll
  for (int i = 0; i < 4; ++i) {
#pragma unroll
    for (int j = 0; j < 4; ++j) {
      const int col = bcol + wc + j * 16 + lr;
      const float bb = bias[col];
#pragma unroll
      for (int r = 0; r < 4; ++r) {
        const int row = brow + wr + i * 16 + ((lane >> 4) << 2) + r;
        const float val = acc[i][j][r] + bb;
        if (EPI == 1) {
          outF[(size_t)row * N + col] = val;
        } else {
          const int b_ = row >> 11, tt = row & 2047;
          const int d = col & 127;
          if (col < 2048) {
            const int hh = col >> 7;
            q[((size_t)((b_ * 16 + hh) * 2048 + tt) << 7) + d] = f2bf(val * QSC);
          } else if (col < 2560) {
            const int hh = (col - 2048) >> 7;
            const int ds = d ^ ((tt & 7) << 3);  // pre-swizzle for attn LDS reads
            kk[((size_t)((b_ * 4 + hh) * 2048 + tt) << 7) + ds] = f2bf(val);
          } else {
            const int hh = (col - 2560) >> 7;
            v[((size_t)((b_ * 4 + hh) * 2048 + tt) << 7) + d] = f2bf(val);
          }
        }
      }
    }
  }
}

// ------------- flash attention (causal, GQA 4:1), swapped-QK^T structure -------------
// grid: (T/128, 16, B), qb reversed (heavy first). 4 waves x 32 q-rows.
// S^T = mfma(K,Q): lane owns q-row = lane&15 -> softmax is 15 fmax + 2 shfl.
// O^T = mfma(V^T, P): running m/l state stays lane-local.
__global__ __launch_bounds__(256, 3)
void attn_fwd(const uint16_t* __restrict__ Q,   // [B*16][T][128], pre-scaled by QSC
              const uint16_t* __restrict__ Kg,  // [B*4][T][128], d XOR-swizzled
              const uint16_t* __restrict__ Vt,  // [B*4][128][T], t XOR-swizzled per 64
              uint16_t* __restrict__ Y,         // [B*T][2048], col offset h*128
              int T) {
  __shared__ __align__(16) uint16_t Ks[64 * 128];
  __shared__ __align__(16) uint16_t Vs[128 * 64];
  __shared__ __align__(16) uint16_t Ps[8][16][72];  // [w*2+mf][q][k], +4 pad (16B rows)
  const int qb = (int)gridDim.x - 1 - (int)blockIdx.x;
  const int h = blockIdx.y, b = blockIdx.z;
  const int hkv = h >> 2;
  const int t = threadIdx.x, w = t >> 6, lane = t & 63;
  const int lr = lane & 15, g = lane >> 4, lk = g << 3;
  const int swz = (lr & 7) << 3;

  const uint16_t* Qp = Q + ((size_t)(b * 16 + h) * T + qb * 128) * 128;
  const uint16_t* Kp = Kg + (size_t)(b * 4 + hkv) * T * 128;
  const uint16_t* Vp = Vt + (size_t)(b * 4 + hkv) * 128 * T;

  // Q fragments (B-operand): lane holds Q[row0+mf*16+lr][kf*32+lk .. +7]
  u16x8 qf[2][4];
#pragma unroll
  for (int mf = 0; mf < 2; ++mf)
#pragma unroll
    for (int kf = 0; kf < 4; ++kf)
      qf[mf][kf] = *(const u16x8*)&Qp[(size_t)(w * 32 + mf * 16 + lr) * 128 + kf * 32 + lk];

  f32x4 o[2][8];  // O^T: lane holds O[q=lr][d = dtile*16 + g*4 + r]
  float mrow[2] = {-3e38f, -3e38f}, lrow[2] = {0.f, 0.f};
#pragma unroll
  for (int mf = 0; mf < 2; ++mf)
#pragma unroll
    for (int d = 0; d < 8; ++d) o[mf][d] = f32x4{0.f, 0.f, 0.f, 0.f};

  const int row0 = qb * 128 + w * 32;
  const int ntiles = 2 * qb + 2;
  const int myn = 2 * qb + 1 + (w >> 1);  // waves 0,1 skip the last (fully-masked) tile
  const int kR = t >> 4, kC = (t & 15) << 3;
  const int vR = t >> 3, vC = (t & 7) << 3;

  for (int tile = 0; tile < ntiles; ++tile) {
    const int kv0 = tile << 6;
#pragma unroll
    for (int it = 0; it < 4; ++it)
      async16(&Ks[(it * 16 + kR) * 128 + kC],
              &Kp[(size_t)(kv0 + it * 16 + kR) * 128 + kC]);
#pragma unroll
    for (int it = 0; it < 4; ++it)
      async16(&Vs[(it * 32 + vR) * 64 + vC],
              &Vp[(size_t)(it * 32 + vR) * T + kv0 + vC]);
    __syncthreads();

    if (tile < myn) {
      // S^T[k=m*16+g*4+r][q=lr] for both mf, K frags read once
      f32x4 s2[2][4];
#pragma unroll
      for (int mf = 0; mf < 2; ++mf)
#pragma unroll
        for (int m = 0; m < 4; ++m) s2[mf][m] = f32x4{0.f, 0.f, 0.f, 0.f};
#pragma unroll
      for (int kf = 0; kf < 4; ++kf) {
        const int cc = (kf * 32 + lk) ^ swz;
#pragma unroll
        for (int m = 0; m < 4; ++m) {
          u16x8 kfr = *(const u16x8*)&Ks[(m * 16 + lr) * 128 + cc];
          s2[0][m] = mfma16(kfr, qf[0][kf], s2[0][m]);
          s2[1][m] = mfma16(kfr, qf[1][kf], s2[1][m]);
        }
      }
      float scl[2];
#pragma unroll
      for (int mf = 0; mf < 2; ++mf) {
        if (kv0 + 63 > row0 + mf * 16) {  // wave-uniform mask check
          const int qrow = row0 + mf * 16 + lr;
#pragma unroll
          for (int m = 0; m < 4; ++m)
#pragma unroll
            for (int r = 0; r < 4; ++r)
              if (kv0 + m * 16 + (g << 2) + r > qrow) s2[mf][m][r] = -3e38f;
        }
        float mx = s2[mf][0][0];
#pragma unroll
        for (int m = 0; m < 4; ++m)
#pragma unroll
          for (int r = 0; r < 4; ++r) mx = fmaxf(mx, s2[mf][m][r]);
        mx = fmaxf(mx, __shfl_xor(mx, 16));
        mx = fmaxf(mx, __shfl_xor(mx, 32));
        const float mnew = fmaxf(mrow[mf], mx);
        const float sc = exp2f(mrow[mf] - mnew);
        float ps = 0.f;
#pragma unroll
        for (int m = 0; m < 4; ++m) {
          u16x4v pk;
#pragma unroll
          for (int r = 0; r < 4; ++r) {
            const float p = exp2f(s2[mf][m][r] - mnew);
            ps += p;
            pk[r] = f2bfn(p);
          }
          *(u16x4v*)&Ps[w * 2 + mf][lr][m * 16 + (g << 2)] = pk;
        }
        ps += __shfl_xor(ps, 16);
        ps += __shfl_xor(ps, 32);
        mrow[mf] = mnew;
        lrow[mf] = lrow[mf] * sc + ps;
        scl[mf] = sc;
      }
#pragma unroll
      for (int mf = 0; mf < 2; ++mf)
#pragma unroll
        for (int d = 0; d < 8; ++d)
#pragma unroll
          for (int r = 0; r < 4; ++r) o[mf][d][r] *= scl[mf];

      u16x8 pa0[2], pa1[2];
#pragma unroll
      for (int kf = 0; kf < 2; ++kf) {
        pa0[kf] = *(const u16x8*)&Ps[w * 2][lr][kf * 32 + lk];
        pa1[kf] = *(const u16x8*)&Ps[w * 2 + 1][lr][kf * 32 + lk];
      }
#pragma unroll
      for (int d = 0; d < 8; ++d) {
#pragma unroll
        for (int kf = 0; kf < 2; ++kf) {
          u16x8 vb = *(const u16x8*)&Vs[(d * 16 + lr) * 64 + ((kf * 32 + lk) ^ swz)];
          o[0][d] = mfma16(vb, pa0[kf], o[0][d]);
          o[1][d] = mfma16(vb, pa1[kf], o[1][d]);
        }
      }
    }
    __syncthreads();
  }

  uint16_t* Yp = Y + ((size_t)(b * T + row0)) * 2048 + h * 128;
#pragma unroll
  for (int mf = 0; mf < 2; ++mf) {
    const float inv = 1.f / lrow[mf];
#pragma unroll
    for (int d = 0; d < 8; ++d) {
      u16x4v pk;
#pragma unroll
      for (int r = 0; r < 4; ++r) pk[r] = f2bfn(o[mf][d][r] * inv);
      *(u16x4v*)&Yp[(size_t)(mf * 16 + lr) * 2048 + d * 16 + (g << 2)] = pk;
    }
  }
}

extern "C" void kernel_launch(void* const* d_in, const int* in_sizes, int n_in,
                              void* d_out, int out_size, void* d_ws, size_t ws_size,
                              hipStream_t stream) {
  const float* x      = (const float*)d_in[0];
  const float* W_attn = (const float*)d_in[1];
  const float* b_attn = (const float*)d_in[2];
  const float* W_proj = (const float*)d_in[3];
  const float* b_proj = (const float*)d_in[4];
  float* out = (float*)d_out;

  const int B = 4, T = 2048, C = 2048, H = 16, HKV = 4, HS = 128;
  const int M = B * T;               // 8192
  const int Nqkv = C + 2 * HKV * HS; // 3072

  uint8_t* ws = (uint8_t*)d_ws;
  size_t off = 0;
  auto alloc = [&](size_t bytes) {
    void* p = ws + off;
    off += (bytes + 255) & ~(size_t)255;
    return p;
  };
  uint16_t* xb  = (uint16_t*)alloc((size_t)M * C * 2);      // reused as yb after qkv
  uint16_t* WaT = (uint16_t*)alloc((size_t)Nqkv * C * 2);
  uint16_t* WpT = (uint16_t*)alloc((size_t)C * C * 2);
  uint16_t* qb  = (uint16_t*)alloc((size_t)B * H * T * HS * 2);
  uint16_t* kb  = (uint16_t*)alloc((size_t)B * HKV * T * HS * 2);
  uint16_t* vb  = (uint16_t*)alloc((size_t)B * HKV * T * HS * 2);
  uint16_t* vtb = (uint16_t*)alloc((size_t)B * HKV * HS * T * 2);
  uint16_t* yb  = xb;

  cvt_f32_bf16<<<2048, 256, 0, stream>>>(x, xb, M * C / 4);
  transp_cvt<<<dim3(Nqkv / 64, C / 64), 256, 0, stream>>>(W_attn, WaT, C, Nqkv);
  transp_cvt<<<dim3(C / 64, C / 64), 256, 0, stream>>>(W_proj, WpT, C, C);
  gemm_bt<0><<<dim3((M / 128) * (Nqkv / 128)), 256, 0, stream>>>(
      xb, WaT, b_attn, nullptr, qb, kb, vb, M, Nqkv, C);
  transp_v<<<dim3(T / 64, 2, B * HKV), 256, 0, stream>>>(vb, vtb, T);
  attn_fwd<<<dim3(T / 128, H, B), 256, 0, stream>>>(qb, kb, vtb, yb, T);
  gemm_bt<1><<<dim3((M / 128) * (C / 128)), 256, 0, stream>>>(
      yb, WpT, b_proj, out, nullptr, nullptr, nullptr, M, C, C);
}

// Round 3
// 556.360 us; speedup vs baseline: 1.0325x; 1.0325x over previous
//
#include <hip/hip_runtime.h>
#include <stdint.h>

#define DEVI __device__ __forceinline__

typedef __attribute__((ext_vector_type(8))) uint16_t u16x8;
typedef __attribute__((ext_vector_type(4))) uint16_t u16x4v;
typedef __attribute__((ext_vector_type(8))) __bf16 bf16x8;
typedef __attribute__((ext_vector_type(4))) float f32x4;

DEVI uint16_t f2bf(float x) {
  union { float f; uint32_t u; } v; v.f = x;
  return (uint16_t)((v.u + 0x7fffu + ((v.u >> 16) & 1u)) >> 16);
}

DEVI uint16_t f2bfn(float f) {
  __bf16 h = (__bf16)f;
  return __builtin_bit_cast(uint16_t, h);
}

DEVI f32x4 mfma16(u16x8 a, u16x8 b, f32x4 c) {
  return __builtin_amdgcn_mfma_f32_16x16x32_bf16(
      __builtin_bit_cast(bf16x8, a), __builtin_bit_cast(bf16x8, b), c, 0, 0, 0);
}

DEVI void async16(void* lds, const void* g) {
  __builtin_amdgcn_global_load_lds(
      (const __attribute__((address_space(1))) uint32_t*)g,
      (__attribute__((address_space(3))) uint32_t*)lds, 16, 0, 0);
}

// 1/sqrt(128) * log2(e): softmax computed in exp2 domain, scale folded into Q.
#define QSC 0.12751742925f

// ---------------- elementwise f32 -> bf16 ----------------
__global__ void cvt_f32_bf16(const float* __restrict__ in, uint16_t* __restrict__ out, int n4) {
  int i = blockIdx.x * blockDim.x + threadIdx.x;
  const int st = gridDim.x * blockDim.x;
  for (; i < n4; i += st) {
    float4 v = ((const float4*)in)[i];
    u16x4v o;
    o[0] = f2bf(v.x); o[1] = f2bf(v.y); o[2] = f2bf(v.z); o[3] = f2bf(v.w);
    ((u16x4v*)out)[i] = o;
  }
}

// ------------- transpose + convert: f32 [K][N] -> bf16 [N][K] -------------
__global__ void transp_cvt(const float* __restrict__ in, uint16_t* __restrict__ out,
                           int K, int N) {
  __shared__ float Ws[64][65];
  const int n0 = blockIdx.x * 64, k0 = blockIdx.y * 64;
  const int t = threadIdx.x;
  const int r = t >> 4, c = (t & 15) << 2;
#pragma unroll
  for (int it = 0; it < 4; ++it) {
    float4 v = *(const float4*)&in[(size_t)(k0 + it * 16 + r) * N + n0 + c];
    Ws[it * 16 + r][c] = v.x; Ws[it * 16 + r][c + 1] = v.y;
    Ws[it * 16 + r][c + 2] = v.z; Ws[it * 16 + r][c + 3] = v.w;
  }
  __syncthreads();
#pragma unroll
  for (int it = 0; it < 4; ++it) {
    const int rr = it * 16 + r;   // n index in tile
    const int cc = c;             // k index in tile
    ushort4 o;
    o.x = f2bf(Ws[cc][rr]);     o.y = f2bf(Ws[cc + 1][rr]);
    o.z = f2bf(Ws[cc + 2][rr]); o.w = f2bf(Ws[cc + 3][rr]);
    *(ushort4*)&out[(size_t)(n0 + rr) * K + k0 + cc] = o;
  }
}

// ---- transpose bf16: [BH][T][128] -> [BH][128][T] (plain layout) ----
__global__ void transp_v(const uint16_t* __restrict__ in, uint16_t* __restrict__ out, int T) {
  __shared__ uint16_t Vsm[64][72];
  const int t0 = blockIdx.x * 64, d0 = blockIdx.y * 64, bh = blockIdx.z;
  const uint16_t* ip = in + (size_t)bh * T * 128;
  uint16_t* op = out + (size_t)bh * 128 * T;
  const int t = threadIdx.x;
  const int r = t >> 3, c = (t & 7) << 3;
#pragma unroll
  for (int it = 0; it < 2; ++it) {
    u16x8 v = *(const u16x8*)&ip[(size_t)(t0 + it * 32 + r) * 128 + d0 + c];
#pragma unroll
    for (int j = 0; j < 8; ++j) Vsm[it * 32 + r][c + j] = v[j];
  }
  __syncthreads();
#pragma unroll
  for (int it = 0; it < 2; ++it) {
    const int rr = it * 32 + r;  // d index in tile
    const int cc = c;            // t index in tile
    u16x8 o;
#pragma unroll
    for (int j = 0; j < 8; ++j) o[j] = Vsm[cc + j][rr];
    *(u16x8*)&op[(size_t)(d0 + rr) * T + t0 + cc] = o;
  }
}

// ------------- GEMM: C[M][N] = A[M][K] * Bt[N][K]^T + bias -------------
// EPI==0: scatter bf16 into q (scaled by QSC) / k / v layouts (plain).
// EPI==1: f32 out[M][N].
template <int EPI>
__global__ __launch_bounds__(256, 2)
void gemm_bt(const uint16_t* __restrict__ A, const uint16_t* __restrict__ Bt,
             const float* __restrict__ bias, float* __restrict__ outF,
             uint16_t* __restrict__ q, uint16_t* __restrict__ kk, uint16_t* __restrict__ v,
             int M, int N, int K) {
  constexpr int BK = 32;
  __shared__ uint16_t As[128 * BK];
  __shared__ uint16_t Bs[128 * BK];
  // bijective XCD swizzle (grid sizes here are multiples of 8)
  int bid = (int)blockIdx.x;
  const int q8 = (int)gridDim.x >> 3;
  bid = (bid & 7) * q8 + (bid >> 3);
  const int nbn = N >> 7;
  const int brow = (bid / nbn) << 7;
  const int bcol = (bid % nbn) << 7;
  const int t = threadIdx.x;
  const int w = t >> 6, lane = t & 63;
  const int wr = ((w >> 1) << 6), wc = ((w & 1) << 6);
  const int lr = lane & 15, lk = (lane >> 4) << 3;
  const int sr = t >> 2;
  const int sc = (t & 3) << 3;

  f32x4 acc[4][4];
#pragma unroll
  for (int i = 0; i < 4; ++i)
#pragma unroll
    for (int j = 0; j < 4; ++j) acc[i][j] = f32x4{0.f, 0.f, 0.f, 0.f};

  const uint16_t* Ap = A + (size_t)(brow + sr) * K + sc;
  const uint16_t* Bp = Bt + (size_t)(bcol + sr) * K + sc;
  const size_t rowskip = (size_t)64 * K;

  for (int k0 = 0; k0 < K; k0 += BK) {
    async16(&As[sr * BK + sc], Ap + k0);
    async16(&As[(64 + sr) * BK + sc], Ap + rowskip + k0);
    async16(&Bs[sr * BK + sc], Bp + k0);
    async16(&Bs[(64 + sr) * BK + sc], Bp + rowskip + k0);
    __syncthreads();
    u16x8 af[4], bf[4];
#pragma unroll
    for (int i = 0; i < 4; ++i) af[i] = *(const u16x8*)&As[(wr + i * 16 + lr) * BK + lk];
#pragma unroll
    for (int j = 0; j < 4; ++j) bf[j] = *(const u16x8*)&Bs[(wc + j * 16 + lr) * BK + lk];
#pragma unroll
    for (int i = 0; i < 4; ++i)
#pragma unroll
      for (int j = 0; j < 4; ++j) acc[i][j] = mfma16(af[i], bf[j], acc[i][j]);
    __syncthreads();
  }

#pragma unroll
  for (int i = 0; i < 4; ++i) {
#pragma unroll
    for (int j = 0; j < 4; ++j) {
      const int col = bcol + wc + j * 16 + lr;
      const float bb = bias[col];
#pragma unroll
      for (int r = 0; r < 4; ++r) {
        const int row = brow + wr + i * 16 + ((lane >> 4) << 2) + r;
        const float val = acc[i][j][r] + bb;
        if (EPI == 1) {
          outF[(size_t)row * N + col] = val;
        } else {
          const int b_ = row >> 11, tt = row & 2047;
          const int d = col & 127;
          if (col < 2048) {
            const int hh = col >> 7;
            q[((size_t)((b_ * 16 + hh) * 2048 + tt) << 7) + d] = f2bf(val * QSC);
          } else if (col < 2560) {
            const int hh = (col - 2048) >> 7;
            kk[((size_t)((b_ * 4 + hh) * 2048 + tt) << 7) + d] = f2bf(val);
          } else {
            const int hh = (col - 2560) >> 7;
            v[((size_t)((b_ * 4 + hh) * 2048 + tt) << 7) + d] = f2bf(val);
          }
        }
      }
    }
  }
}

// ------------- flash attention (causal, GQA 4:1), swapped-QK^T -------------
// 1D grid of 1024; wgid%8 pins each (b,hkv) K/V panel to one XCD's L2.
// Reg-staged K/V double-pipeline (T14): load tile t+1 into regs before
// compute(t); ds_write (XOR-swizzled) after the end barrier.
__global__ __launch_bounds__(256, 3)
void attn_fwd(const uint16_t* __restrict__ Q,   // [B*16][T][128], pre-scaled by QSC
              const uint16_t* __restrict__ Kg,  // [B*4][T][128]
              const uint16_t* __restrict__ Vt,  // [B*4][128][T]
              uint16_t* __restrict__ Y,         // [B*T][2048], col offset h*128
              int T) {
  __shared__ __align__(16) uint16_t Ks[64 * 128];
  __shared__ __align__(16) uint16_t Vs[128 * 64];
  __shared__ __align__(16) uint16_t Ps[8][16][72];  // [w*2+mf][q][k], +4 pad
  // ---- block decode: wgid = j*8 + x; pair = x + 8*((j>>2)&1); qb heavy-first
  const int wgid = (int)blockIdx.x;
  const int x = wgid & 7, j = wgid >> 3;
  const int qb = 15 - (j >> 3);
  const int hloc = j & 3;
  const int pair = x + ((j >> 2) & 1) * 8;   // b*4 + hkv
  const int b = pair >> 2, hkv = pair & 3;
  const int h = hkv * 4 + hloc;

  const int t = threadIdx.x, w = t >> 6, lane = t & 63;
  const int lr = lane & 15, g = lane >> 4, lk = g << 3;
  const int swz = (lr & 7) << 3;

  const uint16_t* Qp = Q + ((size_t)(b * 16 + h) * T + qb * 128) * 128;
  const uint16_t* Kp = Kg + (size_t)(b * 4 + hkv) * T * 128;
  const uint16_t* Vp = Vt + (size_t)(b * 4 + hkv) * 128 * T;

  // Q fragments (B-operand): lane holds Q[row0+mf*16+lr][kf*32+lk .. +7]
  u16x8 qf[2][4];
#pragma unroll
  for (int mf = 0; mf < 2; ++mf)
#pragma unroll
    for (int kf = 0; kf < 4; ++kf)
      qf[mf][kf] = *(const u16x8*)&Qp[(size_t)(w * 32 + mf * 16 + lr) * 128 + kf * 32 + lk];

  f32x4 o[2][8];  // O^T: lane holds O[q=lr][d = dtile*16 + g*4 + r]
  float mrow[2] = {-3e38f, -3e38f}, lrow[2] = {0.f, 0.f};
#pragma unroll
  for (int mf = 0; mf < 2; ++mf)
#pragma unroll
    for (int d = 0; d < 8; ++d) o[mf][d] = f32x4{0.f, 0.f, 0.f, 0.f};

  const int row0 = qb * 128 + w * 32;
  const int ntiles = 2 * qb + 2;
  const int myn = 2 * qb + 1 + (w >> 1);  // waves 0,1 skip last (fully-masked) tile

  // staging geometry (per-thread): K rows it*16+(t>>4), 16B cols (t&15)*8
  //                                V rows it*32+(t>>3), 16B cols (t&7)*8
  const int kSr = t >> 4, kSc = (t & 15) << 3;
  const int vSr = t >> 3, vSc = (t & 7) << 3;
  const int kWc = kSc ^ ((kSr & 7) << 3);   // swizzled LDS col for K write
  const int vWc = vSc ^ ((vSr & 7) << 3);   // swizzled LDS col for V write

  u16x8 kreg[4], vreg[4];
  // prologue: load tile 0 into regs
#pragma unroll
  for (int it = 0; it < 4; ++it)
    kreg[it] = *(const u16x8*)&Kp[(size_t)(it * 16 + kSr) * 128 + kSc];
#pragma unroll
  for (int it = 0; it < 4; ++it)
    vreg[it] = *(const u16x8*)&Vp[(size_t)(it * 32 + vSr) * T + vSc];

  for (int tile = 0; tile < ntiles; ++tile) {
    // write tile t (regs) into LDS, swizzled
#pragma unroll
    for (int it = 0; it < 4; ++it)
      *(u16x8*)&Ks[(it * 16 + kSr) * 128 + kWc] = kreg[it];
#pragma unroll
    for (int it = 0; it < 4; ++it)
      *(u16x8*)&Vs[(it * 32 + vSr) * 64 + vWc] = vreg[it];
    // issue loads for tile t+1 (fly under compute of tile t)
    if (tile + 1 < ntiles) {
      const int kv1 = (tile + 1) << 6;
#pragma unroll
      for (int it = 0; it < 4; ++it)
        kreg[it] = *(const u16x8*)&Kp[(size_t)(kv1 + it * 16 + kSr) * 128 + kSc];
#pragma unroll
      for (int it = 0; it < 4; ++it)
        vreg[it] = *(const u16x8*)&Vp[(size_t)(it * 32 + vSr) * T + kv1 + vSc];
    }
    __syncthreads();

    if (tile < myn) {
      const int kv0 = tile << 6;
      // S^T[k][q=lr]
      f32x4 s2[2][4];
#pragma unroll
      for (int mf = 0; mf < 2; ++mf)
#pragma unroll
        for (int m = 0; m < 4; ++m) s2[mf][m] = f32x4{0.f, 0.f, 0.f, 0.f};
      __builtin_amdgcn_s_setprio(1);
#pragma unroll
      for (int kf = 0; kf < 4; ++kf) {
        const int cc = (kf * 32 + lk) ^ swz;
#pragma unroll
        for (int m = 0; m < 4; ++m) {
          u16x8 kfr = *(const u16x8*)&Ks[(m * 16 + lr) * 128 + cc];
          s2[0][m] = mfma16(kfr, qf[0][kf], s2[0][m]);
          s2[1][m] = mfma16(kfr, qf[1][kf], s2[1][m]);
        }
      }
      __builtin_amdgcn_s_setprio(0);
      float scl[2];
#pragma unroll
      for (int mf = 0; mf < 2; ++mf) {
        if (kv0 + 63 > row0 + mf * 16) {  // wave-uniform mask check
          const int qrow = row0 + mf * 16 + lr;
#pragma unroll
          for (int m = 0; m < 4; ++m)
#pragma unroll
            for (int r = 0; r < 4; ++r)
              if (kv0 + m * 16 + (g << 2) + r > qrow) s2[mf][m][r] = -3e38f;
        }
        float mx = s2[mf][0][0];
#pragma unroll
        for (int m = 0; m < 4; ++m)
#pragma unroll
          for (int r = 0; r < 4; ++r) mx = fmaxf(mx, s2[mf][m][r]);
        mx = fmaxf(mx, __shfl_xor(mx, 16));
        mx = fmaxf(mx, __shfl_xor(mx, 32));
        const float mnew = fmaxf(mrow[mf], mx);
        const float sc = exp2f(mrow[mf] - mnew);
        float ps = 0.f;
#pragma unroll
        for (int m = 0; m < 4; ++m) {
          u16x4v pk;
#pragma unroll
          for (int r = 0; r < 4; ++r) {
            const float p = exp2f(s2[mf][m][r] - mnew);
            ps += p;
            pk[r] = f2bfn(p);
          }
          *(u16x4v*)&Ps[w * 2 + mf][lr][m * 16 + (g << 2)] = pk;
        }
        ps += __shfl_xor(ps, 16);
        ps += __shfl_xor(ps, 32);
        mrow[mf] = mnew;
        lrow[mf] = lrow[mf] * sc + ps;
        scl[mf] = sc;
      }
#pragma unroll
      for (int mf = 0; mf < 2; ++mf)
#pragma unroll
        for (int d = 0; d < 8; ++d)
#pragma unroll
          for (int r = 0; r < 4; ++r) o[mf][d][r] *= scl[mf];

      u16x8 pa0[2], pa1[2];
#pragma unroll
      for (int kf = 0; kf < 2; ++kf) {
        pa0[kf] = *(const u16x8*)&Ps[w * 2][lr][kf * 32 + lk];
        pa1[kf] = *(const u16x8*)&Ps[w * 2 + 1][lr][kf * 32 + lk];
      }
      __builtin_amdgcn_s_setprio(1);
#pragma unroll
      for (int d = 0; d < 8; ++d) {
#pragma unroll
        for (int kf = 0; kf < 2; ++kf) {
          u16x8 vb = *(const u16x8*)&Vs[(d * 16 + lr) * 64 + ((kf * 32 + lk) ^ swz)];
          o[0][d] = mfma16(vb, pa0[kf], o[0][d]);
          o[1][d] = mfma16(vb, pa1[kf], o[1][d]);
        }
      }
      __builtin_amdgcn_s_setprio(0);
    }
    __syncthreads();
  }

  uint16_t* Yp = Y + ((size_t)(b * T + row0)) * 2048 + h * 128;
#pragma unroll
  for (int mf = 0; mf < 2; ++mf) {
    const float inv = 1.f / lrow[mf];
#pragma unroll
    for (int d = 0; d < 8; ++d) {
      u16x4v pk;
#pragma unroll
      for (int r = 0; r < 4; ++r) pk[r] = f2bfn(o[mf][d][r] * inv);
      *(u16x4v*)&Yp[(size_t)(mf * 16 + lr) * 2048 + d * 16 + (g << 2)] = pk;
    }
  }
}

extern "C" void kernel_launch(void* const* d_in, const int* in_sizes, int n_in,
                              void* d_out, int out_size, void* d_ws, size_t ws_size,
                              hipStream_t stream) {
  const float* x      = (const float*)d_in[0];
  const float* W_attn = (const float*)d_in[1];
  const float* b_attn = (const float*)d_in[2];
  const float* W_proj = (const float*)d_in[3];
  const float* b_proj = (const float*)d_in[4];
  float* out = (float*)d_out;

  const int B = 4, T = 2048, C = 2048, H = 16, HKV = 4, HS = 128;
  const int M = B * T;               // 8192
  const int Nqkv = C + 2 * HKV * HS; // 3072

  uint8_t* ws = (uint8_t*)d_ws;
  size_t off = 0;
  auto alloc = [&](size_t bytes) {
    void* p = ws + off;
    off += (bytes + 255) & ~(size_t)255;
    return p;
  };
  uint16_t* xb  = (uint16_t*)alloc((size_t)M * C * 2);      // reused as yb after qkv
  uint16_t* WaT = (uint16_t*)alloc((size_t)Nqkv * C * 2);
  uint16_t* WpT = (uint16_t*)alloc((size_t)C * C * 2);
  uint16_t* qb  = (uint16_t*)alloc((size_t)B * H * T * HS * 2);
  uint16_t* kb  = (uint16_t*)alloc((size_t)B * HKV * T * HS * 2);
  uint16_t* vb  = (uint16_t*)alloc((size_t)B * HKV * T * HS * 2);
  uint16_t* vtb = (uint16_t*)alloc((size_t)B * HKV * HS * T * 2);
  uint16_t* yb  = xb;

  cvt_f32_bf16<<<2048, 256, 0, stream>>>(x, xb, M * C / 4);
  transp_cvt<<<dim3(Nqkv / 64, C / 64), 256, 0, stream>>>(W_attn, WaT, C, Nqkv);
  transp_cvt<<<dim3(C / 64, C / 64), 256, 0, stream>>>(W_proj, WpT, C, C);
  gemm_bt<0><<<dim3((M / 128) * (Nqkv / 128)), 256, 0, stream>>>(
      xb, WaT, b_attn, nullptr, qb, kb, vb, M, Nqkv, C);
  transp_v<<<dim3(T / 64, 2, B * HKV), 256, 0, stream>>>(vb, vtb, T);
  attn_fwd<<<dim3(1024), 256, 0, stream>>>(qb, kb, vtb, yb, T);
  gemm_bt<1><<<dim3((M / 128) * (C / 128)), 256, 0, stream>>>(
      yb, WpT, b_proj, out, nullptr, nullptr, nullptr, M, C, C);
}